// Round 1
// baseline (76.138 us; speedup 1.0000x reference)
//
#include <hip/hip_runtime.h>
#include <math.h>

#define D    2048
#define NB   8
#define BSZ  16
#define ZZ   64
#define HH   256
#define CC   10
#define NPAIR (NB * D)   // 16384
#define GSPLIT 64        // ij-chunks (split-K groups)
#define KC     8         // column chunks of 256 cols

// ---------------------------------------------------------------------------
// K1: seed-emb lookup -> hypernet -> softmax coeffs; fill Mt[pair][b] =
//     coeffs[b,i]*features[b,j]; write attn_map output (identically 1.0).
// One block per batch row b.
// ---------------------------------------------------------------------------
__global__ __launch_bounds__(256) void k_prep(
    const float* __restrict__ feat, const int* __restrict__ seeds,
    const float* __restrict__ semb, const float* __restrict__ statc,
    const float* __restrict__ hw1, const float* __restrict__ hb1,
    const float* __restrict__ hw2, const float* __restrict__ hb2,
    float* __restrict__ Mt, float* __restrict__ out)
{
    int b = blockIdx.x, t = threadIdx.x;
    __shared__ float z[ZZ];
    __shared__ float h[HH];
    __shared__ float lg[NB];
    __shared__ float csh[NB];

    if (t < ZZ) z[t] = semb[seeds[b] * ZZ + t];
    __syncthreads();

    float acc = hb1[t];
    #pragma unroll 8
    for (int u = 0; u < ZZ; ++u) acc = fmaf(z[u], hw1[u * HH + t], acc);
    h[t] = fmaxf(acc, 0.f);
    __syncthreads();

    if (t < NB) {
        float s = hb2[t];
        for (int u = 0; u < HH; ++u) s = fmaf(h[u], hw2[u * NB + t], s);
        lg[t] = s;
    }
    __syncthreads();

    if (t == 0) {
        float m = lg[0];
        for (int i = 1; i < NB; ++i) m = fmaxf(m, lg[i]);
        float e[NB], s = 0.f;
        for (int i = 0; i < NB; ++i) { e[i] = expf(lg[i] - m); s += e[i]; }
        float m2 = statc[0];
        for (int i = 1; i < NB; ++i) m2 = fmaxf(m2, statc[i]);
        float e2[NB], s2 = 0.f;
        for (int i = 0; i < NB; ++i) { e2[i] = expf(statc[i] - m2); s2 += e2[i]; }
        for (int i = 0; i < NB; ++i) csh[i] = e[i] / s + e2[i] / s2;
        // attn_map = softmax over singleton axis == 1.0 exactly
        out[BSZ * CC + b] = 1.0f;
    }
    __syncthreads();

    const float* fb = feat + b * D;
    for (int idx = t; idx < NPAIR; idx += 256) {
        int i = idx >> 11;          // D == 2048 == 2^11
        int j = idx & (D - 1);
        Mt[idx * BSZ + b] = csh[i] * fb[j];
    }
}

// ---------------------------------------------------------------------------
// K2: split-K GEMM  part[g][b][k] = sum_{pair in chunk g} Mt[pair][b]*wv[pair][k]
// Grid (KC=8, GSPLIT=64); block = 1024 threads = 16 waves.
// Each wave: 16 (i,j) rows x 256 cols (float4/lane), 16 batch accumulators.
// LDS-reduce the 16 waves, write one partial slice per (g, b, col-range).
// ---------------------------------------------------------------------------
__global__ __launch_bounds__(1024) void k_partial(
    const float* __restrict__ wv, const float* __restrict__ Mt,
    float* __restrict__ part)
{
    int kc   = blockIdx.x;                                    // 0..7
    int g    = blockIdx.y;                                    // 0..63
    int t    = threadIdx.x;
    int wave = __builtin_amdgcn_readfirstlane(t >> 6);        // 0..15, wave-uniform
    int lane = t & 63;
    int col  = kc * 256 + lane * 4;
    int pair_base = g * 256 + wave * 16;

    float4 acc[BSZ];
    #pragma unroll
    for (int b = 0; b < BSZ; ++b) acc[b] = make_float4(0.f, 0.f, 0.f, 0.f);

    #pragma unroll 4
    for (int it = 0; it < 16; ++it) {
        int p = pair_base + it;
        const float* ap = Mt + p * BSZ;                       // wave-uniform -> s_load
        const float4 w = *reinterpret_cast<const float4*>(wv + (size_t)p * D + col);
        #pragma unroll
        for (int b = 0; b < BSZ; ++b) {
            float a = ap[b];
            acc[b].x = fmaf(a, w.x, acc[b].x);
            acc[b].y = fmaf(a, w.y, acc[b].y);
            acc[b].z = fmaf(a, w.z, acc[b].z);
            acc[b].w = fmaf(a, w.w, acc[b].w);
        }
    }

    // reduce across the 16 waves, 4 batch rows per round (64 KiB LDS)
    __shared__ float4 sh[4][16][64];
    for (int round = 0; round < 4; ++round) {
        #pragma unroll
        for (int bb = 0; bb < 4; ++bb)
            sh[bb][wave][lane] = acc[round * 4 + bb];
        __syncthreads();
        if (wave < 4) {
            float4 s = sh[wave][0][lane];
            #pragma unroll
            for (int sw = 1; sw < 16; ++sw) {
                float4 x = sh[wave][sw][lane];
                s.x += x.x; s.y += x.y; s.z += x.z; s.w += x.w;
            }
            int b = round * 4 + wave;
            *reinterpret_cast<float4*>(part + ((size_t)(g * BSZ + b)) * D + col) = s;
        }
        __syncthreads();
    }
}

// ---------------------------------------------------------------------------
// K3: v[b][k] = sum_g part[g][b][k]
// ---------------------------------------------------------------------------
__global__ __launch_bounds__(256) void k_reduce(
    const float* __restrict__ part, float* __restrict__ v)
{
    int idx = blockIdx.x * 256 + threadIdx.x;   // 0 .. 16*2048-1
    int b = idx >> 11;
    int k = idx & (D - 1);
    float s0 = 0.f, s1 = 0.f, s2 = 0.f, s3 = 0.f;
    for (int g = 0; g < GSPLIT; g += 4) {
        s0 += part[((size_t)((g + 0) * BSZ + b)) * D + k];
        s1 += part[((size_t)((g + 1) * BSZ + b)) * D + k];
        s2 += part[((size_t)((g + 2) * BSZ + b)) * D + k];
        s3 += part[((size_t)((g + 3) * BSZ + b)) * D + k];
    }
    v[idx] = (s0 + s1) + (s2 + s3);
}

// ---------------------------------------------------------------------------
// K4: logits[b][c] = sum_k v[b][k]*cw[k][c] + cb[c]   (pooled == v)
// ---------------------------------------------------------------------------
__global__ __launch_bounds__(256) void k_cls(
    const float* __restrict__ v, const float* __restrict__ cw,
    const float* __restrict__ cb, float* __restrict__ out)
{
    int b = blockIdx.x, t = threadIdx.x;
    int wave = t >> 6, lane = t & 63;
    float lacc[CC];
    #pragma unroll
    for (int c = 0; c < CC; ++c) lacc[c] = 0.f;
    for (int k = t; k < D; k += 256) {
        float vv = v[b * D + k];
        const float* cwr = cw + k * CC;
        #pragma unroll
        for (int c = 0; c < CC; ++c) lacc[c] = fmaf(vv, cwr[c], lacc[c]);
    }
    __shared__ float sred[4][CC];
    #pragma unroll
    for (int c = 0; c < CC; ++c) {
        float val = lacc[c];
        for (int off = 32; off > 0; off >>= 1) val += __shfl_down(val, off);
        if (lane == 0) sred[wave][c] = val;
    }
    __syncthreads();
    if (t < CC)
        out[b * CC + t] = sred[0][t] + sred[1][t] + sred[2][t] + sred[3][t] + cb[t];
}

// ---------------------------------------------------------------------------
extern "C" void kernel_launch(void* const* d_in, const int* in_sizes, int n_in,
                              void* d_out, int out_size, void* d_ws, size_t ws_size,
                              hipStream_t stream)
{
    const float* feat  = (const float*)d_in[0];
    const int*   seeds = (const int*)  d_in[1];
    const float* semb  = (const float*)d_in[2];
    const float* statc = (const float*)d_in[3];
    const float* hw1   = (const float*)d_in[4];
    const float* hb1   = (const float*)d_in[5];
    const float* hw2   = (const float*)d_in[6];
    const float* hb2   = (const float*)d_in[7];
    // d_in[8] = wq, d_in[9] = wk: DEAD — attn softmax over a singleton axis is
    // identically 1, so pooled == v and q,k never reach the output.
    const float* wv    = (const float*)d_in[10];
    const float* cw    = (const float*)d_in[11];
    const float* cb    = (const float*)d_in[12];
    float* out = (float*)d_out;

    float* Mt   = (float*)d_ws;                       // 16384*16 fl = 1 MiB
    float* part = Mt + (size_t)NPAIR * BSZ;           // 64*16*2048 fl = 8 MiB
    float* v    = part + (size_t)GSPLIT * BSZ * D;    // 32768 fl = 128 KiB

    hipLaunchKernelGGL(k_prep, dim3(BSZ), dim3(256), 0, stream,
                       feat, seeds, semb, statc, hw1, hb1, hw2, hb2, Mt, out);
    hipLaunchKernelGGL(k_partial, dim3(KC, GSPLIT), dim3(1024), 0, stream,
                       wv, Mt, part);
    hipLaunchKernelGGL(k_reduce, dim3(BSZ * D / 256), dim3(256), 0, stream,
                       part, v);
    hipLaunchKernelGGL(k_cls, dim3(BSZ), dim3(256), 0, stream,
                       v, cw, cb, out);
}

// Round 2
// 70.854 us; speedup vs baseline: 1.0746x; 1.0746x over previous
//
#include <hip/hip_runtime.h>
#include <math.h>

#define D    2048
#define NB   8
#define BSZ  16
#define ZZ   64
#define HH   256
#define CC   10
#define NPAIR (NB * D)   // 16384
#define GSPLIT 64        // ij-chunks (split-K groups)
#define KC     8         // column chunks of 256 cols

// ---------------------------------------------------------------------------
// K1 (k_mt): each of 64 blocks redundantly computes the tiny hypernetwork
// (seed-emb -> 2-layer MLP -> softmax + static softmax) into csh[16][8],
// then writes its 256-pair chunk of Mt[pair][b] = csh[b][i]*feat[b][j]
// as CONTIGUOUS 64 B per thread (4x float4) -- no scatter.
// Block 0 also writes attn_map (identically 1.0: softmax over singleton axis).
// ---------------------------------------------------------------------------
__global__ __launch_bounds__(256) void k_mt(
    const float* __restrict__ feat, const int* __restrict__ seeds,
    const float* __restrict__ semb, const float* __restrict__ statc,
    const float* __restrict__ hw1, const float* __restrict__ hb1,
    const float* __restrict__ hw2, const float* __restrict__ hb2,
    float* __restrict__ Mt, float* __restrict__ out)
{
    int t = threadIdx.x, blk = blockIdx.x;
    __shared__ float zs[BSZ][ZZ];     // 4 KB
    __shared__ float hs[BSZ][HH];     // 16 KB
    __shared__ float lgs[BSZ][NB];
    __shared__ float cshs[BSZ][NB];

    for (int e = t; e < BSZ * ZZ; e += 256) {
        int b = e >> 6, u = e & (ZZ - 1);
        zs[b][u] = semb[seeds[b] * ZZ + u];
    }
    __syncthreads();

    // h[b][t] for all b, reading each hw1 column once (u outer, b inner)
    {
        float acc[BSZ];
        float bias = hb1[t];
        #pragma unroll
        for (int b = 0; b < BSZ; ++b) acc[b] = bias;
        #pragma unroll 4
        for (int u = 0; u < ZZ; ++u) {
            float w = hw1[u * HH + t];
            #pragma unroll
            for (int b = 0; b < BSZ; ++b) acc[b] = fmaf(zs[b][u], w, acc[b]);
        }
        #pragma unroll
        for (int b = 0; b < BSZ; ++b) hs[b][t] = fmaxf(acc[b], 0.f);
    }
    __syncthreads();

    if (t < BSZ * NB) {          // 128 threads: one (b, c) logit each
        int b = t >> 3, c = t & (NB - 1);
        float s = hb2[c];
        #pragma unroll 4
        for (int u = 0; u < HH; ++u) s = fmaf(hs[b][u], hw2[u * NB + c], s);
        lgs[b][c] = s;
    }
    __syncthreads();

    if (t < BSZ) {
        int b = t;
        float m = lgs[b][0];
        #pragma unroll
        for (int i = 1; i < NB; ++i) m = fmaxf(m, lgs[b][i]);
        float e[NB], s = 0.f;
        #pragma unroll
        for (int i = 0; i < NB; ++i) { e[i] = expf(lgs[b][i] - m); s += e[i]; }
        float m2 = statc[0];
        #pragma unroll
        for (int i = 1; i < NB; ++i) m2 = fmaxf(m2, statc[i]);
        float e2[NB], s2 = 0.f;
        #pragma unroll
        for (int i = 0; i < NB; ++i) { e2[i] = expf(statc[i] - m2); s2 += e2[i]; }
        #pragma unroll
        for (int i = 0; i < NB; ++i) cshs[b][i] = e[i] / s + e2[i] / s2;
        if (blk == 0) out[BSZ * CC + b] = 1.0f;   // attn_map == 1 exactly
    }
    __syncthreads();

    // Mt chunk: pair p = blk*256 + t; i uniform per block, j consecutive
    int p = blk * 256 + t;
    int i = blk >> 3;
    int j = (blk & 7) * 256 + t;
    float vals[BSZ];
    #pragma unroll
    for (int b = 0; b < BSZ; ++b) vals[b] = cshs[b][i] * feat[b * D + j];
    float4* dst = reinterpret_cast<float4*>(Mt + (size_t)p * BSZ);
    dst[0] = make_float4(vals[0],  vals[1],  vals[2],  vals[3]);
    dst[1] = make_float4(vals[4],  vals[5],  vals[6],  vals[7]);
    dst[2] = make_float4(vals[8],  vals[9],  vals[10], vals[11]);
    dst[3] = make_float4(vals[12], vals[13], vals[14], vals[15]);
}

// ---------------------------------------------------------------------------
// K2: split-K GEMM  part[g][b][k] = sum_{pair in chunk g} Mt[pair][b]*wv[pair][k]
// Grid (KC=8, GSPLIT=64); block = 1024 threads = 16 waves.
// Each wave: 16 (i,j) rows x 256 cols (float4/lane), 16 batch accumulators.
// Mt row (64 B) loads as s_load_dwordx16; wv streams coalesced 16 B/lane.
// ---------------------------------------------------------------------------
__global__ __launch_bounds__(1024) void k_partial(
    const float* __restrict__ wv, const float* __restrict__ Mt,
    float* __restrict__ part)
{
    int kc   = blockIdx.x;                                    // 0..7
    int g    = blockIdx.y;                                    // 0..63
    int t    = threadIdx.x;
    int wave = __builtin_amdgcn_readfirstlane(t >> 6);        // 0..15, wave-uniform
    int lane = t & 63;
    int col  = kc * 256 + lane * 4;
    int pair_base = g * 256 + wave * 16;

    float4 acc[BSZ];
    #pragma unroll
    for (int b = 0; b < BSZ; ++b) acc[b] = make_float4(0.f, 0.f, 0.f, 0.f);

    #pragma unroll 4
    for (int it = 0; it < 16; ++it) {
        int p = pair_base + it;
        const float* ap = Mt + (size_t)p * BSZ;               // wave-uniform -> s_load
        const float4 w = *reinterpret_cast<const float4*>(wv + (size_t)p * D + col);
        #pragma unroll
        for (int b = 0; b < BSZ; ++b) {
            float a = ap[b];
            acc[b].x = fmaf(a, w.x, acc[b].x);
            acc[b].y = fmaf(a, w.y, acc[b].y);
            acc[b].z = fmaf(a, w.z, acc[b].z);
            acc[b].w = fmaf(a, w.w, acc[b].w);
        }
    }

    // reduce across the 16 waves, 4 batch rows per round (64 KiB LDS)
    __shared__ float4 sh[4][16][64];
    for (int round = 0; round < 4; ++round) {
        #pragma unroll
        for (int bb = 0; bb < 4; ++bb)
            sh[bb][wave][lane] = acc[round * 4 + bb];
        __syncthreads();
        if (wave < 4) {
            float4 s = sh[wave][0][lane];
            #pragma unroll
            for (int sw = 1; sw < 16; ++sw) {
                float4 x = sh[wave][sw][lane];
                s.x += x.x; s.y += x.y; s.z += x.z; s.w += x.w;
            }
            int b = round * 4 + wave;
            *reinterpret_cast<float4*>(part + ((size_t)(g * BSZ + b)) * D + col) = s;
        }
        __syncthreads();
    }
}

// ---------------------------------------------------------------------------
// K3: v[b][k] = sum_g part[g][b][k]   (8 independent streams for MLP)
// ---------------------------------------------------------------------------
__global__ __launch_bounds__(256) void k_reduce(
    const float* __restrict__ part, float* __restrict__ v)
{
    int idx = blockIdx.x * 256 + threadIdx.x;   // 0 .. 16*2048-1
    int b = idx >> 11;
    int k = idx & (D - 1);
    float s[8];
    #pragma unroll
    for (int r = 0; r < 8; ++r) s[r] = 0.f;
    for (int g = 0; g < GSPLIT; g += 8) {
        #pragma unroll
        for (int r = 0; r < 8; ++r)
            s[r] += part[((size_t)((g + r) * BSZ + b)) * D + k];
    }
    v[idx] = ((s[0] + s[1]) + (s[2] + s[3])) + ((s[4] + s[5]) + (s[6] + s[7]));
}

// ---------------------------------------------------------------------------
// K4: logits[b][c] = sum_k v[b][k]*cw[k][c] + cb[c]   (pooled == v)
// ---------------------------------------------------------------------------
__global__ __launch_bounds__(256) void k_cls(
    const float* __restrict__ v, const float* __restrict__ cw,
    const float* __restrict__ cb, float* __restrict__ out)
{
    int b = blockIdx.x, t = threadIdx.x;
    int wave = t >> 6, lane = t & 63;
    float lacc[CC];
    #pragma unroll
    for (int c = 0; c < CC; ++c) lacc[c] = 0.f;
    for (int k = t; k < D; k += 256) {
        float vv = v[b * D + k];
        const float* cwr = cw + k * CC;
        #pragma unroll
        for (int c = 0; c < CC; ++c) lacc[c] = fmaf(vv, cwr[c], lacc[c]);
    }
    __shared__ float sred[4][CC];
    #pragma unroll
    for (int c = 0; c < CC; ++c) {
        float val = lacc[c];
        for (int off = 32; off > 0; off >>= 1) val += __shfl_down(val, off);
        if (lane == 0) sred[wave][c] = val;
    }
    __syncthreads();
    if (t < CC)
        out[b * CC + t] = sred[0][t] + sred[1][t] + sred[2][t] + sred[3][t] + cb[t];
}

// ---------------------------------------------------------------------------
extern "C" void kernel_launch(void* const* d_in, const int* in_sizes, int n_in,
                              void* d_out, int out_size, void* d_ws, size_t ws_size,
                              hipStream_t stream)
{
    const float* feat  = (const float*)d_in[0];
    const int*   seeds = (const int*)  d_in[1];
    const float* semb  = (const float*)d_in[2];
    const float* statc = (const float*)d_in[3];
    const float* hw1   = (const float*)d_in[4];
    const float* hb1   = (const float*)d_in[5];
    const float* hw2   = (const float*)d_in[6];
    const float* hb2   = (const float*)d_in[7];
    // d_in[8] = wq, d_in[9] = wk: DEAD — attn softmax over a singleton axis is
    // identically 1, so pooled == v and q,k never reach the output.
    const float* wv    = (const float*)d_in[10];
    const float* cw    = (const float*)d_in[11];
    const float* cb    = (const float*)d_in[12];
    float* out = (float*)d_out;

    float* Mt   = (float*)d_ws;                       // 16384*16 fl = 1 MiB
    float* part = Mt + (size_t)NPAIR * BSZ;           // 64*16*2048 fl = 8 MiB
    float* v    = part + (size_t)GSPLIT * BSZ * D;    // 32768 fl = 128 KiB

    hipLaunchKernelGGL(k_mt, dim3(NPAIR / 256), dim3(256), 0, stream,
                       feat, seeds, semb, statc, hw1, hb1, hw2, hb2, Mt, out);
    hipLaunchKernelGGL(k_partial, dim3(KC, GSPLIT), dim3(1024), 0, stream,
                       wv, Mt, part);
    hipLaunchKernelGGL(k_reduce, dim3(BSZ * D / 256), dim3(256), 0, stream,
                       part, v);
    hipLaunchKernelGGL(k_cls, dim3(BSZ), dim3(256), 0, stream,
                       v, cw, cb, out);
}

// Round 3
// 65.399 us; speedup vs baseline: 1.1642x; 1.0834x over previous
//
#include <hip/hip_runtime.h>
#include <math.h>

#define D    2048
#define NB   8
#define BSZ  16
#define ZZ   64
#define HH   256
#define CC   10
#define NPAIR (NB * D)   // 16384
#define GSPLIT 64        // pair-chunks (split-K groups) of 256 pairs
#define KC     8         // column chunks of 256 cols

// ---------------------------------------------------------------------------
// K1 (k_mt): each of 64 blocks redundantly computes the tiny hypernetwork
// (seed-emb -> 2-layer MLP -> softmax + static softmax) into csh[16][8],
// then writes its 256-pair chunk of Mt[pair][b] = csh[b][i]*feat[b][j]
// as CONTIGUOUS 64 B per thread (4x float4).
// Block 0 also writes attn_map (identically 1.0: softmax over singleton axis).
// ---------------------------------------------------------------------------
__global__ __launch_bounds__(256) void k_mt(
    const float* __restrict__ feat, const int* __restrict__ seeds,
    const float* __restrict__ semb, const float* __restrict__ statc,
    const float* __restrict__ hw1, const float* __restrict__ hb1,
    const float* __restrict__ hw2, const float* __restrict__ hb2,
    float* __restrict__ Mt, float* __restrict__ out)
{
    int t = threadIdx.x, blk = blockIdx.x;
    __shared__ float zs[BSZ][ZZ];
    __shared__ float hs[BSZ][HH];
    __shared__ float lgs[BSZ][NB];
    __shared__ float cshs[BSZ][NB];

    for (int e = t; e < BSZ * ZZ; e += 256) {
        int b = e >> 6, u = e & (ZZ - 1);
        zs[b][u] = semb[seeds[b] * ZZ + u];
    }
    __syncthreads();

    {
        float acc[BSZ];
        float bias = hb1[t];
        #pragma unroll
        for (int b = 0; b < BSZ; ++b) acc[b] = bias;
        #pragma unroll 4
        for (int u = 0; u < ZZ; ++u) {
            float w = hw1[u * HH + t];
            #pragma unroll
            for (int b = 0; b < BSZ; ++b) acc[b] = fmaf(zs[b][u], w, acc[b]);
        }
        #pragma unroll
        for (int b = 0; b < BSZ; ++b) hs[b][t] = fmaxf(acc[b], 0.f);
    }
    __syncthreads();

    if (t < BSZ * NB) {          // 128 threads: one (b, c) logit each
        int b = t >> 3, c = t & (NB - 1);
        float s = hb2[c];
        #pragma unroll 4
        for (int u = 0; u < HH; ++u) s = fmaf(hs[b][u], hw2[u * NB + c], s);
        lgs[b][c] = s;
    }
    __syncthreads();

    if (t < BSZ) {
        int b = t;
        float m = lgs[b][0];
        #pragma unroll
        for (int i = 1; i < NB; ++i) m = fmaxf(m, lgs[b][i]);
        float e[NB], s = 0.f;
        #pragma unroll
        for (int i = 0; i < NB; ++i) { e[i] = expf(lgs[b][i] - m); s += e[i]; }
        float m2 = statc[0];
        #pragma unroll
        for (int i = 1; i < NB; ++i) m2 = fmaxf(m2, statc[i]);
        float e2[NB], s2 = 0.f;
        #pragma unroll
        for (int i = 0; i < NB; ++i) { e2[i] = expf(statc[i] - m2); s2 += e2[i]; }
        #pragma unroll
        for (int i = 0; i < NB; ++i) cshs[b][i] = e[i] / s + e2[i] / s2;
        if (blk == 0) out[BSZ * CC + b] = 1.0f;   // attn_map == 1 exactly
    }
    __syncthreads();

    int p = blk * 256 + t;
    int i = blk >> 3;
    int j = (blk & 7) * 256 + t;
    float vals[BSZ];
    #pragma unroll
    for (int b = 0; b < BSZ; ++b) vals[b] = cshs[b][i] * feat[b * D + j];
    float4* dst = reinterpret_cast<float4*>(Mt + (size_t)p * BSZ);
    dst[0] = make_float4(vals[0],  vals[1],  vals[2],  vals[3]);
    dst[1] = make_float4(vals[4],  vals[5],  vals[6],  vals[7]);
    dst[2] = make_float4(vals[8],  vals[9],  vals[10], vals[11]);
    dst[3] = make_float4(vals[12], vals[13], vals[14], vals[15]);
}

// ---------------------------------------------------------------------------
// K2: split-K GEMM  part[g][b][k] = sum_{pair in chunk g} Mt[pair][b]*wv[pair][k]
// Grid (KC=8, GSPLIT=64); block = 512 threads = 8 waves, 32 pairs/wave.
// Mt chunk staged in LDS (no SMEM in hot loop -> in-order fine-grained
// lgkmcnt instead of out-of-order s_load drains). wv streams 16 B/lane.
// 48 KiB LDS, __launch_bounds__(512,4) -> 2 blocks/CU, grid = 1 full pass.
// ---------------------------------------------------------------------------
__global__ __launch_bounds__(512, 4) void k_partial(
    const float* __restrict__ wv, const float* __restrict__ Mt,
    float* __restrict__ part)
{
    int kc   = blockIdx.x;                                    // 0..7
    int g    = blockIdx.y;                                    // 0..63
    int t    = threadIdx.x;
    int wave = t >> 6;
    int lane = t & 63;
    int col  = kc * 256 + lane * 4;

    __shared__ float mt[256 * BSZ];     // 16 KB: Mt[g*256 .. g*256+255][0..15]
    __shared__ float4 sh[4][8][64];     // 32 KB reduce buffer

    {   // stage Mt chunk: 4096 contiguous floats, coalesced float4
        const float4* src = reinterpret_cast<const float4*>(Mt + (size_t)g * 256 * BSZ);
        float4* dst = reinterpret_cast<float4*>(mt);
        dst[t]       = src[t];
        dst[t + 512] = src[t + 512];
    }
    __syncthreads();

    float4 acc[BSZ];
    #pragma unroll
    for (int b = 0; b < BSZ; ++b) acc[b] = make_float4(0.f, 0.f, 0.f, 0.f);

    int pair0 = wave * 32;
    const float* wp = wv + ((size_t)(g * 256 + pair0)) * D + col;

    #pragma unroll 4
    for (int it = 0; it < 32; ++it) {
        const float4 w = *reinterpret_cast<const float4*>(wp + (size_t)it * D);
        const float4* ap4 = reinterpret_cast<const float4*>(mt + (pair0 + it) * BSZ);
        float4 a0 = ap4[0], a1 = ap4[1], a2 = ap4[2], a3 = ap4[3];  // ds_read_b128 x4, broadcast
        const float am[BSZ] = {a0.x, a0.y, a0.z, a0.w, a1.x, a1.y, a1.z, a1.w,
                               a2.x, a2.y, a2.z, a2.w, a3.x, a3.y, a3.z, a3.w};
        #pragma unroll
        for (int b = 0; b < BSZ; ++b) {
            float a = am[b];
            acc[b].x = fmaf(a, w.x, acc[b].x);
            acc[b].y = fmaf(a, w.y, acc[b].y);
            acc[b].z = fmaf(a, w.z, acc[b].z);
            acc[b].w = fmaf(a, w.w, acc[b].w);
        }
    }

    // reduce across the 8 waves, 4 batch rows per round
    for (int round = 0; round < 4; ++round) {
        #pragma unroll
        for (int bb = 0; bb < 4; ++bb)
            sh[bb][wave][lane] = acc[round * 4 + bb];
        __syncthreads();
        if (wave < 4) {
            float4 s = sh[wave][0][lane];
            #pragma unroll
            for (int sw = 1; sw < 8; ++sw) {
                float4 x = sh[wave][sw][lane];
                s.x += x.x; s.y += x.y; s.z += x.z; s.w += x.w;
            }
            int b = round * 4 + wave;
            *reinterpret_cast<float4*>(part + ((size_t)(g * BSZ + b)) * D + col) = s;
        }
        __syncthreads();
    }
}

// ---------------------------------------------------------------------------
// K3: v[b][k] = sum_g part[g][b][k]   (16 independent load streams)
// ---------------------------------------------------------------------------
__global__ __launch_bounds__(256) void k_reduce(
    const float* __restrict__ part, float* __restrict__ v)
{
    int idx = blockIdx.x * 256 + threadIdx.x;   // 0 .. 16*2048-1
    int b = idx >> 11;
    int k = idx & (D - 1);
    float s[16];
    #pragma unroll
    for (int r = 0; r < 16; ++r) s[r] = 0.f;
    for (int g = 0; g < GSPLIT; g += 16) {
        #pragma unroll
        for (int r = 0; r < 16; ++r)
            s[r] += part[((size_t)((g + r) * BSZ + b)) * D + k];
    }
    float t0 = ((s[0] + s[1]) + (s[2] + s[3])) + ((s[4] + s[5]) + (s[6] + s[7]));
    float t1 = ((s[8] + s[9]) + (s[10] + s[11])) + ((s[12] + s[13]) + (s[14] + s[15]));
    v[idx] = t0 + t1;
}

// ---------------------------------------------------------------------------
// K4: logits[b][c] = sum_k v[b][k]*cw[k][c] + cb[c]   (pooled == v)
// ---------------------------------------------------------------------------
__global__ __launch_bounds__(256) void k_cls(
    const float* __restrict__ v, const float* __restrict__ cw,
    const float* __restrict__ cb, float* __restrict__ out)
{
    int b = blockIdx.x, t = threadIdx.x;
    int wave = t >> 6, lane = t & 63;
    float lacc[CC];
    #pragma unroll
    for (int c = 0; c < CC; ++c) lacc[c] = 0.f;
    for (int k = t; k < D; k += 256) {
        float vv = v[b * D + k];
        const float* cwr = cw + k * CC;
        #pragma unroll
        for (int c = 0; c < CC; ++c) lacc[c] = fmaf(vv, cwr[c], lacc[c]);
    }
    __shared__ float sred[4][CC];
    #pragma unroll
    for (int c = 0; c < CC; ++c) {
        float val = lacc[c];
        for (int off = 32; off > 0; off >>= 1) val += __shfl_down(val, off);
        if (lane == 0) sred[wave][c] = val;
    }
    __syncthreads();
    if (t < CC)
        out[b * CC + t] = sred[0][t] + sred[1][t] + sred[2][t] + sred[3][t] + cb[t];
}

// ---------------------------------------------------------------------------
extern "C" void kernel_launch(void* const* d_in, const int* in_sizes, int n_in,
                              void* d_out, int out_size, void* d_ws, size_t ws_size,
                              hipStream_t stream)
{
    const float* feat  = (const float*)d_in[0];
    const int*   seeds = (const int*)  d_in[1];
    const float* semb  = (const float*)d_in[2];
    const float* statc = (const float*)d_in[3];
    const float* hw1   = (const float*)d_in[4];
    const float* hb1   = (const float*)d_in[5];
    const float* hw2   = (const float*)d_in[6];
    const float* hb2   = (const float*)d_in[7];
    // d_in[8] = wq, d_in[9] = wk: DEAD — attn softmax over a singleton axis is
    // identically 1, so pooled == v and q,k never reach the output.
    const float* wv    = (const float*)d_in[10];
    const float* cw    = (const float*)d_in[11];
    const float* cb    = (const float*)d_in[12];
    float* out = (float*)d_out;

    float* Mt   = (float*)d_ws;                       // 16384*16 fl = 1 MiB
    float* part = Mt + (size_t)NPAIR * BSZ;           // 64*16*2048 fl = 8 MiB
    float* v    = part + (size_t)GSPLIT * BSZ * D;    // 32768 fl = 128 KiB

    hipLaunchKernelGGL(k_mt, dim3(NPAIR / 256), dim3(256), 0, stream,
                       feat, seeds, semb, statc, hw1, hb1, hw2, hb2, Mt, out);
    hipLaunchKernelGGL(k_partial, dim3(KC, GSPLIT), dim3(512), 0, stream,
                       wv, Mt, part);
    hipLaunchKernelGGL(k_reduce, dim3(BSZ * D / 256), dim3(256), 0, stream,
                       part, v);
    hipLaunchKernelGGL(k_cls, dim3(BSZ), dim3(256), 0, stream,
                       v, cw, cb, out);
}

// Round 4
// 52.321 us; speedup vs baseline: 1.4552x; 1.2500x over previous
//
#include <hip/hip_runtime.h>
#include <math.h>

#define D    2048
#define NB   8
#define BSZ  16
#define ZZ   64
#define HH   256
#define CC   10
#define NPAIR (NB * D)   // 16384
#define GSPLIT 64        // pair-chunks of 256 pairs
#define KC     8         // column chunks of 256 cols

// ---------------------------------------------------------------------------
// K1 (k_coeff): ONE block, 256 threads. Hypernet -> coeffs^T[NB][BSZ] in ws.
// Also initializes out: logits[b][c] = cb[c] (k_tail atomically accumulates),
// attn_map = 1.0 exactly (softmax over a singleton axis).
// ---------------------------------------------------------------------------
__global__ __launch_bounds__(256) void k_coeff(
    const int* __restrict__ seeds, const float* __restrict__ semb,
    const float* __restrict__ statc,
    const float* __restrict__ hw1, const float* __restrict__ hb1,
    const float* __restrict__ hw2, const float* __restrict__ hb2,
    const float* __restrict__ cb,
    float* __restrict__ coeffT, float* __restrict__ out)
{
    int t = threadIdx.x;
    __shared__ float zs[BSZ][ZZ];
    __shared__ float hs[BSZ][HH];
    __shared__ float lgs[BSZ][NB];

    for (int e = t; e < BSZ * ZZ; e += 256) {
        int b = e >> 6, u = e & (ZZ - 1);
        zs[b][u] = semb[seeds[b] * ZZ + u];
    }
    __syncthreads();

    {   // h[b][t] for all b; hw1 column t coalesced
        float acc[BSZ];
        float bias = hb1[t];
        #pragma unroll
        for (int b = 0; b < BSZ; ++b) acc[b] = bias;
        #pragma unroll 8
        for (int u = 0; u < ZZ; ++u) {
            float w = hw1[u * HH + t];
            #pragma unroll
            for (int b = 0; b < BSZ; ++b) acc[b] = fmaf(zs[b][u], w, acc[b]);
        }
        #pragma unroll
        for (int b = 0; b < BSZ; ++b) hs[b][t] = fmaxf(acc[b], 0.f);
    }
    __syncthreads();

    {   // logits: 256 threads = 16 b x 8 c x 2 halves of the u-range
        int b = t >> 4, c = (t >> 1) & 7, half = t & 1;
        float s = half ? 0.f : hb2[c];
        int u0 = half * (HH / 2);
        #pragma unroll 16
        for (int u = 0; u < HH / 2; ++u)
            s = fmaf(hs[b][u0 + u], hw2[(u0 + u) * NB + c], s);
        s += __shfl_xor(s, 1);
        if (!half) lgs[b][c] = s;
    }
    __syncthreads();

    if (t < BSZ) {
        int b = t;
        float m = lgs[b][0];
        #pragma unroll
        for (int i = 1; i < NB; ++i) m = fmaxf(m, lgs[b][i]);
        float e[NB], s = 0.f;
        #pragma unroll
        for (int i = 0; i < NB; ++i) { e[i] = expf(lgs[b][i] - m); s += e[i]; }
        float m2 = statc[0];
        #pragma unroll
        for (int i = 1; i < NB; ++i) m2 = fmaxf(m2, statc[i]);
        float e2[NB], s2 = 0.f;
        #pragma unroll
        for (int i = 0; i < NB; ++i) { e2[i] = expf(statc[i] - m2); s2 += e2[i]; }
        #pragma unroll
        for (int i = 0; i < NB; ++i) coeffT[i * BSZ + b] = e[i] / s + e2[i] / s2;
    }
    // out init: logits = cb (accumulated by k_tail), attn = 1.0
    if (t < BSZ * CC) out[t] = cb[t - (t / CC) * CC];
    else if (t < BSZ * CC + BSZ) out[t] = 1.0f;
}

// ---------------------------------------------------------------------------
// K2 (k_main): part[g][b][k] = cf[b] * sum_{p in chunk g} feat[b][j(p)]*wv[p][k]
// i(p) is UNIFORM within a g-chunk, so the coefficient scales the epilogue.
// Grid (KC=8, GSPLIT=64); 512 thr = 8 waves, 32 pairs/wave, float4 cols/lane.
// feat slice (16 KB) staged transposed in LDS; explicit component FMAs
// (no indexable local array -> no scratch risk).
// ---------------------------------------------------------------------------
__global__ __launch_bounds__(512, 4) void k_main(
    const float* __restrict__ wv, const float* __restrict__ feat,
    const float* __restrict__ coeffT, float* __restrict__ part)
{
    int kc   = blockIdx.x;                                    // 0..7
    int g    = blockIdx.y;                                    // 0..63
    int t    = threadIdx.x;
    int wave = t >> 6;
    int lane = t & 63;
    int col  = kc * 256 + lane * 4;

    __shared__ float ft[256 * BSZ];     // 16 KB: ft[j][b], j local pair
    __shared__ float4 sh[4][8][64];     // 32 KB reduce buffer

    {   // stage feat slice transposed: ft[j*16+b] = feat[b][jbase+j]
        int jbase = (g & 7) * 256;
        int b = t & 15, j = t >> 4;     // j in 0..31 (+32 per round)
        #pragma unroll
        for (int r = 0; r < 8; ++r)
            ft[t + 512 * r] = feat[b * D + jbase + j + 32 * r];
    }
    __syncthreads();

    float4 acc[BSZ];
    #pragma unroll
    for (int b = 0; b < BSZ; ++b) acc[b] = make_float4(0.f, 0.f, 0.f, 0.f);

    int pair0 = wave * 32;
    const float* wp = wv + ((size_t)(g * 256 + pair0)) * D + col;
    const float* fp = ft + pair0 * BSZ;

    #pragma unroll 4
    for (int it = 0; it < 32; ++it) {
        const float4 w = *reinterpret_cast<const float4*>(wp + (size_t)it * D);
        const float4* ap4 = reinterpret_cast<const float4*>(fp + it * BSZ);
        float4 a0 = ap4[0], a1 = ap4[1], a2 = ap4[2], a3 = ap4[3];  // broadcast b128
#define FMA4(ACC, A) \
        ACC.x = fmaf(A, w.x, ACC.x); ACC.y = fmaf(A, w.y, ACC.y); \
        ACC.z = fmaf(A, w.z, ACC.z); ACC.w = fmaf(A, w.w, ACC.w);
        FMA4(acc[0],  a0.x) FMA4(acc[1],  a0.y) FMA4(acc[2],  a0.z) FMA4(acc[3],  a0.w)
        FMA4(acc[4],  a1.x) FMA4(acc[5],  a1.y) FMA4(acc[6],  a1.z) FMA4(acc[7],  a1.w)
        FMA4(acc[8],  a2.x) FMA4(acc[9],  a2.y) FMA4(acc[10], a2.z) FMA4(acc[11], a2.w)
        FMA4(acc[12], a3.x) FMA4(acc[13], a3.y) FMA4(acc[14], a3.z) FMA4(acc[15], a3.w)
#undef FMA4
    }

    // cross-wave reduce; scale by cf[b] = coeffT[i_g][b] at the single writer
    const float* cfp = coeffT + (g >> 3) * BSZ;
    for (int round = 0; round < 4; ++round) {
        #pragma unroll
        for (int bb = 0; bb < 4; ++bb)
            sh[bb][wave][lane] = acc[round * 4 + bb];
        __syncthreads();
        if (wave < 4) {
            float4 s = sh[wave][0][lane];
            #pragma unroll
            for (int sw = 1; sw < 8; ++sw) {
                float4 x = sh[wave][sw][lane];
                s.x += x.x; s.y += x.y; s.z += x.z; s.w += x.w;
            }
            int b = round * 4 + wave;
            float cf = cfp[b];
            s.x *= cf; s.y *= cf; s.z *= cf; s.w *= cf;
            *reinterpret_cast<float4*>(part + ((size_t)(g * BSZ + b)) * D + col) = s;
        }
        __syncthreads();
    }
}

// ---------------------------------------------------------------------------
// K3 (k_tail): fused split-K reduce + classifier.
// 128 blocks = 16 b x 8 col-chunks; thread t owns col k = kc8*256+t.
// v_bk = sum_g part[g][b][k]; partial logits via cw; block-reduce; 10
// atomicAdds into cb-preinitialized out[b][:]. (fp32 atomic order jitter
// ~1e-6 << 1.92 threshold.)
// ---------------------------------------------------------------------------
__global__ __launch_bounds__(256) void k_tail(
    const float* __restrict__ part, const float* __restrict__ cw,
    float* __restrict__ out)
{
    int b = blockIdx.x >> 3, kc8 = blockIdx.x & 7;
    int t = threadIdx.x;
    int wave = t >> 6, lane = t & 63;
    int k = kc8 * 256 + t;

    float s = 0.f;
    {
        float ps[8];
        #pragma unroll
        for (int r = 0; r < 8; ++r) ps[r] = 0.f;
        for (int g = 0; g < GSPLIT; g += 8) {
            #pragma unroll
            for (int r = 0; r < 8; ++r)
                ps[r] += part[((size_t)((g + r) * BSZ + b)) * D + k];
        }
        s = ((ps[0] + ps[1]) + (ps[2] + ps[3])) + ((ps[4] + ps[5]) + (ps[6] + ps[7]));
    }

    float lacc[CC];
    const float* cwr = cw + (size_t)k * CC;
    #pragma unroll
    for (int c = 0; c < CC; ++c) lacc[c] = s * cwr[c];

    __shared__ float sred[4][CC];
    #pragma unroll
    for (int c = 0; c < CC; ++c) {
        float val = lacc[c];
        for (int off = 32; off > 0; off >>= 1) val += __shfl_down(val, off);
        if (lane == 0) sred[wave][c] = val;
    }
    __syncthreads();
    if (t < CC)
        atomicAdd(&out[b * CC + t],
                  sred[0][t] + sred[1][t] + sred[2][t] + sred[3][t]);
}

// ---------------------------------------------------------------------------
extern "C" void kernel_launch(void* const* d_in, const int* in_sizes, int n_in,
                              void* d_out, int out_size, void* d_ws, size_t ws_size,
                              hipStream_t stream)
{
    const float* feat  = (const float*)d_in[0];
    const int*   seeds = (const int*)  d_in[1];
    const float* semb  = (const float*)d_in[2];
    const float* statc = (const float*)d_in[3];
    const float* hw1   = (const float*)d_in[4];
    const float* hb1   = (const float*)d_in[5];
    const float* hw2   = (const float*)d_in[6];
    const float* hb2   = (const float*)d_in[7];
    // d_in[8] = wq, d_in[9] = wk: DEAD — attn softmax over a singleton axis is
    // identically 1, so pooled == v and q,k never reach the output.
    const float* wv    = (const float*)d_in[10];
    const float* cw    = (const float*)d_in[11];
    const float* cb    = (const float*)d_in[12];
    float* out = (float*)d_out;

    float* coeffT = (float*)d_ws;                     // 128 floats (pad 256)
    float* part   = coeffT + 256;                     // 64*16*2048 fl = 8 MiB

    hipLaunchKernelGGL(k_coeff, dim3(1), dim3(256), 0, stream,
                       seeds, semb, statc, hw1, hb1, hw2, hb2, cb, coeffT, out);
    hipLaunchKernelGGL(k_main, dim3(KC, GSPLIT), dim3(512), 0, stream,
                       wv, feat, coeffT, part);
    hipLaunchKernelGGL(k_tail, dim3(BSZ * KC), dim3(256), 0, stream,
                       part, cw, out);
}